// Round 5
// baseline (3445.079 us; speedup 1.0000x reference)
//
#include <hip/hip_runtime.h>
#include <math.h>

#define T_DIM 2048
#define S_DIM 2048
#define D_DIM 64
#define BH_DIM 32
#define U_SEL 614
#define LOG_S_D 7.624618986159398
#define LOG2E_F 1.4426950408889634f
#define LN2_D 0.6931471805599453
#define SCL_Q (0.125f * LOG2E_F)  // q scale folded with log2e: scores in log2 domain

typedef __attribute__((ext_vector_type(8))) short bf16x8;
typedef __attribute__((ext_vector_type(4))) short bf16x4;
typedef __attribute__((ext_vector_type(4))) float f32x4;

__device__ __forceinline__ unsigned short bf16_rne(float x) {
  unsigned u = __float_as_uint(x);
  u += 0x7FFF + ((u >> 16) & 1);
  return (unsigned short)(u >> 16);
}
__device__ __forceinline__ float bf16_to_f(unsigned short h) {
  return __uint_as_float(((unsigned)h) << 16);
}

// ====== convert: K -> 64-row tiles [hi 4096 | lo 4096] swizzled; V -> V^T images; zero(out) ======
// kimg tile (16 KB): element (r,d) hi at r*64 + ((d>>3)^(r&7))*8 + (d&7); lo at +4096.
// vt tile (16 KB): [64 d][128 s]: (d,s) at d*128 + (((s>>3)^(d&15))*8 + (s&7).
__global__ __launch_bounds__(256) void convert_kernel(
    const float* __restrict__ kin, const float* __restrict__ vin,
    unsigned short* __restrict__ kimg, unsigned short* __restrict__ vt_g,
    float* __restrict__ out) {
  __shared__ float vld[128][65];
  const int jb = blockIdx.x;
  const int tid = threadIdx.x;
  if (jb < 1024) {  // K: 32 bh x 32 tiles of 64 rows
    const int bh = jb >> 5, tl = jb & 31;
    const float* src = kin + ((size_t)bh * 2048 + tl * 64) * 64;
    unsigned short* dst = kimg + (size_t)(bh * 32 + tl) * 8192;
#pragma unroll
    for (int g = 0; g < 2; ++g) {
      const int flat = g * 256 + tid;  // 512 chunks = 64 rows x 8
      const int r = flat >> 3, c = flat & 7;
      const float4 f0 = *(const float4*)(src + r * 64 + c * 8);
      const float4 f1 = *(const float4*)(src + r * 64 + c * 8 + 4);
      const float xs[8] = {f0.x, f0.y, f0.z, f0.w, f1.x, f1.y, f1.z, f1.w};
      bf16x8 hv, lv;
#pragma unroll
      for (int j = 0; j < 8; ++j) {
        const unsigned short h = bf16_rne(xs[j]);
        hv[j] = (short)h;
        lv[j] = (short)bf16_rne(xs[j] - bf16_to_f(h));
      }
      const int base = (r << 6) + ((c ^ (r & 7)) << 3);
      *(bf16x8*)(dst + base) = hv;
      *(bf16x8*)(dst + 4096 + base) = lv;
    }
  } else if (jb < 1536) {  // V^T
    const int jv = jb - 1024;
    const int bh = jv >> 4, tl = jv & 15;
    const float* src = vin + ((size_t)bh * 2048 + tl * 128) * 64;
#pragma unroll
    for (int g = 0; g < 8; ++g) {
      const int f = g * 256 + tid;
      const int r = f >> 4, c4 = f & 15;
      const float4 x = *(const float4*)(src + r * 64 + c4 * 4);
      vld[r][c4 * 4 + 0] = x.x;
      vld[r][c4 * 4 + 1] = x.y;
      vld[r][c4 * 4 + 2] = x.z;
      vld[r][c4 * 4 + 3] = x.w;
    }
    __syncthreads();
    unsigned short* dst = vt_g + (size_t)(bh * 16 + tl) * 8192;
#pragma unroll
    for (int g = 0; g < 4; ++g) {
      const int oc = g * 256 + tid;
      const int d = oc >> 4, cc = oc & 15;
      bf16x8 hv;
#pragma unroll
      for (int j = 0; j < 8; ++j) hv[j] = (short)bf16_rne(vld[cc * 8 + j][d]);
      *(bf16x8*)(dst + (d << 7) + (((cc ^ (d & 15))) << 3)) = hv;
    }
  } else {  // zero d_out
    float4* o4 = (float4*)out;
    const size_t b = (size_t)(jb - 1536);
#pragma unroll
    for (int g = 0; g < 8; ++g)
      o4[b * 2048 + g * 256 + tid] = make_float4(0.f, 0.f, 0.f, 0.f);
  }
}

// ====== Phase A: KL scores. Barrier-free K-loop: K = A-operand (wave-private s-slice,
// global->register frags), q = B-operand (persistent registers). bf16x3 MFMA. ======
// grid 1024: bh = b&31 (XCD-local), t0 = (b>>5)*64
__global__ __launch_bounds__(256, 2) void kl_score_mfma(
    const float* __restrict__ q, const unsigned short* __restrict__ kimg,
    float* __restrict__ klout) {
  __shared__ float zs[4][64];
  __shared__ float wsh[4][64];
  const int b = blockIdx.x;
  const int bh = b & 31;
  const int t0 = (b >> 5) * 64;
  const int tid = threadIdx.x;
  const int lane = tid & 63, w = tid >> 6, quad = lane >> 4, l15 = lane & 15;
  const float* qb = q + (size_t)bh * (2048 * 64);
  const unsigned short* kb = kimg + (size_t)bh * (32 * 8192);

  // q B-fragments, hi/lo split in-register, scaled by 0.125*log2e (persistent all 16 iters)
  bf16x8 qfh[4][2], qfl[4][2];
#pragma unroll
  for (int nt = 0; nt < 4; ++nt) {
    const float* qp = qb + (size_t)(t0 + nt * 16 + l15) * 64;
#pragma unroll
    for (int kc = 0; kc < 2; ++kc) {
      const float4 f0 = *(const float4*)(qp + kc * 32 + quad * 8);
      const float4 f1 = *(const float4*)(qp + kc * 32 + quad * 8 + 4);
      const float xs[8] = {f0.x, f0.y, f0.z, f0.w, f1.x, f1.y, f1.z, f1.w};
      bf16x8 hv, lv;
#pragma unroll
      for (int j = 0; j < 8; ++j) {
        const float x = xs[j] * SCL_Q;
        const unsigned short h = bf16_rne(x);
        hv[j] = (short)h;
        lv[j] = (short)bf16_rne(x - bf16_to_f(h));
      }
      qfh[nt][kc] = hv;
      qfl[nt][kc] = lv;
    }
  }

  float zacc[4] = {0.f, 0.f, 0.f, 0.f};
  float wacc[4] = {0.f, 0.f, 0.f, 0.f};

  // K A-fragments: wave w owns s-rows [t*128 + w*32, +32) each iter; 2-deep register dbuf
  bf16x8 kah[2][2][2], kal[2][2][2];  // [buf][mt][kc]
  const int rbase = (w & 1) * 32;
  auto ldk = [&](int t, int buf) {
    const unsigned short* ib = kb + (size_t)(2 * t + (w >> 1)) * 8192;
#pragma unroll
    for (int mt = 0; mt < 2; ++mt) {
      const int row = rbase + mt * 16 + l15;
      const int rb = row << 6, sw = row & 7;
#pragma unroll
      for (int kc = 0; kc < 2; ++kc) {
        const int off = rb + (((kc * 4 + quad) ^ sw) << 3);
        kah[buf][mt][kc] = *(const bf16x8*)(ib + off);
        kal[buf][mt][kc] = *(const bf16x8*)(ib + 4096 + off);
      }
    }
  };
  ldk(0, 0);

#pragma unroll 2
  for (int t = 0; t < 16; ++t) {
    const int cur = t & 1;
    if (t < 15) ldk(t + 1, cur ^ 1);

    // S^T[m=s][n=t] via bf16x3: kh*qh + kl*qh + kh*ql
    f32x4 sacc[2][4];
#pragma unroll
    for (int mt = 0; mt < 2; ++mt)
#pragma unroll
      for (int nt = 0; nt < 4; ++nt) sacc[mt][nt] = (f32x4){0.f, 0.f, 0.f, 0.f};
#pragma unroll
    for (int mt = 0; mt < 2; ++mt)
#pragma unroll
      for (int nt = 0; nt < 4; ++nt) {
        f32x4 c = sacc[mt][nt];
#pragma unroll
        for (int kc = 0; kc < 2; ++kc) {
          c = __builtin_amdgcn_mfma_f32_16x16x32_bf16(kah[cur][mt][kc], qfh[nt][kc], c, 0, 0, 0);
          c = __builtin_amdgcn_mfma_f32_16x16x32_bf16(kal[cur][mt][kc], qfh[nt][kc], c, 0, 0, 0);
          c = __builtin_amdgcn_mfma_f32_16x16x32_bf16(kah[cur][mt][kc], qfl[nt][kc], c, 0, 0, 0);
        }
        sacc[mt][nt] = c;
      }

    // no-max epilogue (log2 domain): e = 2^t, W2 += e*t; per-lane accum (col = t = l15)
#pragma unroll
    for (int nt = 0; nt < 4; ++nt) {
      float zp = 0.f, wp = 0.f;
#pragma unroll
      for (int mt = 0; mt < 2; ++mt)
#pragma unroll
        for (int r = 0; r < 4; ++r) {
          const float tt = sacc[mt][nt][r];
          const float e = exp2f(tt);
          zp += e;
          wp = fmaf(e, tt, wp);
        }
      zacc[nt] += zp;
      wacc[nt] += wp;
    }
  }

  // reduce over quads (shfl) then waves (LDS), compute kl, write
#pragma unroll
  for (int nt = 0; nt < 4; ++nt) {
    float z = zacc[nt], wv = wacc[nt];
    z += __shfl_xor(z, 16);
    z += __shfl_xor(z, 32);
    wv += __shfl_xor(wv, 16);
    wv += __shfl_xor(wv, 32);
    if (quad == 0) {
      zs[w][nt * 16 + l15] = z;
      wsh[w][nt * 16 + l15] = wv;
    }
  }
  __syncthreads();
  if (tid < 64) {
    const double Z = (double)zs[0][tid] + (double)zs[1][tid] + (double)zs[2][tid] + (double)zs[3][tid];
    const double W = (double)wsh[0][tid] + (double)wsh[1][tid] + (double)wsh[2][tid] + (double)wsh[3][tid];
    klout[(size_t)bh * 2048 + t0 + tid] = (float)(LN2_D * (W / Z) - log(Z) + LOG_S_D);
  }
}

// ====== Phase B: exact top-614 per (b,h), bitonic, 1024 threads ======
__global__ __launch_bounds__(1024) void topk_kernel(const float* __restrict__ kl,
                                                    int* __restrict__ topk) {
  __shared__ float sv[2048];
  __shared__ int si[2048];
  const int bh = blockIdx.x;
  const int tid = threadIdx.x;
  for (int i = tid; i < 2048; i += 1024) { sv[i] = kl[(size_t)bh * 2048 + i]; si[i] = i; }
  __syncthreads();
  for (int kk = 2; kk <= 2048; kk <<= 1) {
    for (int j = kk >> 1; j > 0; j >>= 1) {
      const int p = tid;
      const int i = ((p & ~(j - 1)) << 1) | (p & (j - 1));
      const int pr = i | j;
      const float v1 = sv[i], v2 = sv[pr];
      const int i1 = si[i], i2 = si[pr];
      const bool beforePI = (v2 > v1) || (v2 == v1 && i2 < i1);
      const bool dirDesc = ((i & kk) == 0);
      const bool doSwap = dirDesc ? beforePI : !beforePI;
      if (doSwap) { sv[i] = v2; sv[pr] = v1; si[i] = i2; si[pr] = i1; }
      __syncthreads();
    }
  }
  for (int i = tid; i < U_SEL; i += 1024) topk[bh * U_SEL + i] = si[i];
}

// ====== Phase C: barrier-free bf16 MFMA attention on selected rows, no-max softmax ======
// K/V frags per-wave private -> direct global->register loads; P in per-wave LDS (lgkmcnt only).
// grid 320: bh = b&31 (XCD-local), l0 = (b>>5)*64
__global__ __launch_bounds__(256, 2) void sparse_attn_mfma(
    const float* __restrict__ q, const unsigned short* __restrict__ kimg,
    const unsigned short* __restrict__ vt_g, const int* __restrict__ topk,
    float* __restrict__ out) {
  __shared__ __align__(16) unsigned short ps[4][64 * 40];  // 20 KB, per-wave P [qr][s_local]
  __shared__ float obuf[64 * 64];                          // 16 KB
  __shared__ float zred[4][64];                            // 1 KB
  const int b = blockIdx.x;
  const int bh = b & 31;
  const int l0 = (b >> 5) * 64;
  const int tid = threadIdx.x;
  const int lane = tid & 63, w = tid >> 6, quad = lane >> 4, l15 = lane & 15;
  const float* qb = q + (size_t)bh * (2048 * 64);
  const unsigned short* kb = kimg + (size_t)bh * (32 * 8192);
  const unsigned short* vtb = vt_g + (size_t)bh * (16 * 8192);
  const int* tkb = topk + bh * U_SEL;

  // gather selected q rows directly into B-fragments (scaled by 0.125*log2e, hi only)
  bf16x8 qf[4][2];
#pragma unroll
  for (int nt = 0; nt < 4; ++nt) {
    const int l = l0 + nt * 16 + l15;
    const int row = tkb[l < U_SEL ? l : (U_SEL - 1)];
    const float* qp = qb + (size_t)row * 64;
#pragma unroll
    for (int kc = 0; kc < 2; ++kc) {
      const float4 f0 = *(const float4*)(qp + kc * 32 + quad * 8);
      const float4 f1 = *(const float4*)(qp + kc * 32 + quad * 8 + 4);
      const float xs[8] = {f0.x, f0.y, f0.z, f0.w, f1.x, f1.y, f1.z, f1.w};
      bf16x8 hv;
#pragma unroll
      for (int j = 0; j < 8; ++j) hv[j] = (short)bf16_rne(xs[j] * SCL_Q);
      qf[nt][kc] = hv;
    }
  }

  float zrun[4] = {0.f, 0.f, 0.f, 0.f};
  f32x4 oacc[4][4];
#pragma unroll
  for (int a = 0; a < 4; ++a)
#pragma unroll
    for (int d = 0; d < 4; ++d) oacc[a][d] = (f32x4){0.f, 0.f, 0.f, 0.f};

  bf16x8 ka[2][2][2];  // [buf][mt][kc], K hi only
  bf16x8 vbf[2][4];    // [buf][dt]
  const int rbase = (w & 1) * 32;
  const int cc = w * 4 + quad;
  auto ldkv = [&](int t, int buf) {
    const unsigned short* ib = kb + (size_t)(2 * t + (w >> 1)) * 8192;
#pragma unroll
    for (int mt = 0; mt < 2; ++mt) {
      const int row = rbase + mt * 16 + l15;
      const int rb = row << 6, sw = row & 7;
#pragma unroll
      for (int kc = 0; kc < 2; ++kc)
        ka[buf][mt][kc] = *(const bf16x8*)(ib + rb + (((kc * 4 + quad) ^ sw) << 3));
    }
    const unsigned short* vb2 = vtb + (size_t)t * 8192;
#pragma unroll
    for (int dt = 0; dt < 4; ++dt) {
      const int d = dt * 16 + l15;
      vbf[buf][dt] = *(const bf16x8*)(vb2 + (d << 7) + ((cc ^ (d & 15)) << 3));
    }
  };
  ldkv(0, 0);

#pragma unroll 2
  for (int t = 0; t < 16; ++t) {
    const int cur = t & 1;
    if (t < 15) ldkv(t + 1, cur ^ 1);

    // S^T[m=s][n=qr]; wave w owns s-slice [t*128 + w*32, +32)
    f32x4 sacc[2][4];
#pragma unroll
    for (int mt = 0; mt < 2; ++mt)
#pragma unroll
      for (int nt = 0; nt < 4; ++nt) {
        f32x4 c = (f32x4){0.f, 0.f, 0.f, 0.f};
        c = __builtin_amdgcn_mfma_f32_16x16x32_bf16(ka[cur][mt][0], qf[nt][0], c, 0, 0, 0);
        c = __builtin_amdgcn_mfma_f32_16x16x32_bf16(ka[cur][mt][1], qf[nt][1], c, 0, 0, 0);
        sacc[mt][nt] = c;
      }

    // no-max softmax: p = 2^t; P -> per-wave LDS (C-layout rows = 4 consecutive s per qr)
#pragma unroll
    for (int nt = 0; nt < 4; ++nt) {
      float zl = 0.f;
#pragma unroll
      for (int mt = 0; mt < 2; ++mt) {
        bf16x4 pw;
#pragma unroll
        for (int r = 0; r < 4; ++r) {
          const float p = exp2f(sacc[mt][nt][r]);
          zl += p;
          pw[r] = (short)bf16_rne(p);
        }
        *(bf16x4*)&ps[w][(nt * 16 + l15) * 40 + mt * 16 + quad * 4] = pw;
      }
      zrun[nt] += zl;
    }

    // PV: O[qr][d] += P[qr][s]·V^T[d][s]
#pragma unroll
    for (int mtq = 0; mtq < 4; ++mtq) {
      const bf16x8 pa = *(const bf16x8*)&ps[w][(mtq * 16 + l15) * 40 + quad * 8];
#pragma unroll
      for (int dt = 0; dt < 4; ++dt)
        oacc[mtq][dt] = __builtin_amdgcn_mfma_f32_16x16x32_bf16(pa, vbf[cur][dt], oacc[mtq][dt], 0, 0, 0);
    }
  }

  // merge: Z over quads (shfl) + waves (LDS); O over waves (LDS atomics)
#pragma unroll
  for (int nt = 0; nt < 4; ++nt) {
    float z = zrun[nt];
    z += __shfl_xor(z, 16);
    z += __shfl_xor(z, 32);
    if (quad == 0) zred[w][nt * 16 + l15] = z;
  }
  for (int i = tid; i < 64 * 64; i += 256) obuf[i] = 0.f;
  __syncthreads();
#pragma unroll
  for (int mtq = 0; mtq < 4; ++mtq)
#pragma unroll
    for (int r = 0; r < 4; ++r) {
      const int qr = mtq * 16 + quad * 4 + r;
#pragma unroll
      for (int dt = 0; dt < 4; ++dt)
        atomicAdd(&obuf[qr * 64 + dt * 16 + l15], oacc[mtq][dt][r]);
    }
  __syncthreads();
  {
    const int qr = tid >> 2, seg = tid & 3;
    const int l = l0 + qr;
    if (l < U_SEL) {
      const float Zt = zred[0][qr] + zred[1][qr] + zred[2][qr] + zred[3][qr];
      const float inv = 1.0f / Zt;
      const int row = tkb[l];
      float* op = &out[((size_t)bh * T_DIM + row) * 64 + seg * 16];
      const float* ob = &obuf[qr * 64 + seg * 16];
#pragma unroll
      for (int j = 0; j < 4; ++j) {
        float4 o;
        o.x = ob[j * 4 + 0] * inv;
        o.y = ob[j * 4 + 1] * inv;
        o.z = ob[j * 4 + 2] * inv;
        o.w = ob[j * 4 + 3] * inv;
        *(float4*)&op[j * 4] = o;
      }
    }
  }
}

extern "C" void kernel_launch(void* const* d_in, const int* in_sizes, int n_in,
                              void* d_out, int out_size, void* d_ws, size_t ws_size,
                              hipStream_t stream) {
  const float* q = (const float*)d_in[0];
  const float* k = (const float*)d_in[1];
  const float* v = (const float*)d_in[2];
  float* out = (float*)d_out;
  // workspace: kl 256 KB | topk 78 KB | kimg 16 MB | vt 8 MB  (~25.3 MB)
  char* ws = (char*)d_ws;
  float* kl = (float*)ws;
  int* topk = (int*)(ws + 262144);
  unsigned short* kimg = (unsigned short*)(ws + 1310720);
  unsigned short* vt_g = (unsigned short*)(ws + 18087936);

  convert_kernel<<<dim3(2048), dim3(256), 0, stream>>>(k, v, kimg, vt_g, out);
  kl_score_mfma<<<dim3(1024), dim3(256), 0, stream>>>(q, kimg, kl);
  topk_kernel<<<dim3(BH_DIM), dim3(1024), 0, stream>>>(kl, topk);
  sparse_attn_mfma<<<dim3(320), dim3(256), 0, stream>>>(q, kimg, vt_g, topk, out);
}

// Round 6
// 903.003 us; speedup vs baseline: 3.8151x; 3.8151x over previous
//
#include <hip/hip_runtime.h>
#include <math.h>

#define T_DIM 2048
#define S_DIM 2048
#define D_DIM 64
#define BH_DIM 32
#define U_SEL 614
#define LT_N 10
#define LOG_S_D 7.624618986159398
#define LOG2E_F 1.4426950408889634f
#define LN2_D 0.6931471805599453
#define SCL_Q (0.125f * LOG2E_F)  // q scale folded with log2e: scores in log2 domain

// ---- workspace layout (bytes) ----
#define WS_ZW 0u               // float2[32][2048] = 1,048,576
#define WS_CNT 1048576u        // int[32] = 128  (zeroed with zw)
#define WS_TOPK 1048704u       // int[32][614] = 78,592
#define WS_PO 1127424u         // float[640][4096] = 10,485,760
#define WS_PZ 11613184u        // float[640][64] = 163,840
#define WS_KIMG 11777024u      // 16,777,216
#define WS_VT 28554240u        // 8,388,608  (end ~35.2 MB)

typedef __attribute__((ext_vector_type(8))) short bf16x8;
typedef __attribute__((ext_vector_type(4))) short bf16x4;
typedef __attribute__((ext_vector_type(4))) float f32x4;

__device__ __forceinline__ unsigned short bf16_rne(float x) {
  unsigned u = __float_as_uint(x);
  u += 0x7FFF + ((u >> 16) & 1);
  return (unsigned short)(u >> 16);
}
__device__ __forceinline__ float bf16_to_f(unsigned short h) {
  return __uint_as_float(((unsigned)h) << 16);
}

#define GLD_LDS16(g, l)                                                        \
  __builtin_amdgcn_global_load_lds(                                            \
      (const __attribute__((address_space(1))) unsigned int*)(const void*)(g), \
      (__attribute__((address_space(3))) unsigned int*)(void*)(l), 16, 0, 0)

// stage 16 KB image: 4 waves x 4 instr x 64 lanes x 16 B
__device__ __forceinline__ void stage_img16(const unsigned short* __restrict__ g,
                                            unsigned short* l, int lane, int w) {
#pragma unroll
  for (int it = 0; it < 4; ++it) {
    const int chunk = it * 4 + w;
    GLD_LDS16((const char*)g + chunk * 1024 + lane * 16, (char*)l + chunk * 1024);
  }
}
// stage 8 KB image
__device__ __forceinline__ void stage_img8(const unsigned short* __restrict__ g,
                                           unsigned short* l, int lane, int w) {
#pragma unroll
  for (int it = 0; it < 2; ++it) {
    const int chunk = it * 4 + w;
    GLD_LDS16((const char*)g + chunk * 1024 + lane * 16, (char*)l + chunk * 1024);
  }
}

// swizzled image, 64-wide rows: element (r,d) at r*64 + ((d>>3)^(r&7))*8 + (d&7)
__device__ __forceinline__ bf16x8 ldfrag_sw(const unsigned short* buf, int row, int chunk) {
  return *(const bf16x8*)(buf + (row << 6) + (((chunk) ^ (row & 7)) << 3));
}
// two stacked 64-row images (rows 0..127)
__device__ __forceinline__ bf16x8 ldfrag_k128(const unsigned short* buf, int row, int chunk) {
  return *(const bf16x8*)(buf + ((row >> 6) << 12) + ((row & 63) << 6) +
                          (((chunk) ^ (row & 7)) << 3));
}

// ====== convert: K -> 64-row tiles [hi 8KB | lo 8KB] swizzled; V -> V^T images;
//        zero(out); zero(zw + counters) ======
__global__ __launch_bounds__(256) void convert_kernel(
    const float* __restrict__ kin, const float* __restrict__ vin,
    unsigned short* __restrict__ kimg, unsigned short* __restrict__ vt_g,
    float* __restrict__ out, float4* __restrict__ wszero) {
  __shared__ float vld[128][65];
  const int jb = blockIdx.x;
  const int tid = threadIdx.x;
  if (jb < 1024) {  // K: 32 bh x 32 tiles of 64 rows
    const int bh = jb >> 5, tl = jb & 31;
    const float* src = kin + ((size_t)bh * 2048 + tl * 64) * 64;
    unsigned short* dst = kimg + (size_t)(bh * 32 + tl) * 8192;
#pragma unroll
    for (int g = 0; g < 2; ++g) {
      const int flat = g * 256 + tid;  // 512 chunks = 64 rows x 8
      const int r = flat >> 3, c = flat & 7;
      const float4 f0 = *(const float4*)(src + r * 64 + c * 8);
      const float4 f1 = *(const float4*)(src + r * 64 + c * 8 + 4);
      const float xs[8] = {f0.x, f0.y, f0.z, f0.w, f1.x, f1.y, f1.z, f1.w};
      bf16x8 hv, lv;
#pragma unroll
      for (int j = 0; j < 8; ++j) {
        const unsigned short h = bf16_rne(xs[j]);
        hv[j] = (short)h;
        lv[j] = (short)bf16_rne(xs[j] - bf16_to_f(h));
      }
      const int base = (r << 6) + ((c ^ (r & 7)) << 3);
      *(bf16x8*)(dst + base) = hv;
      *(bf16x8*)(dst + 4096 + base) = lv;
    }
  } else if (jb < 1536) {  // V^T: [64 d][128 s] bf16, chunk ^ (d&15)
    const int jv = jb - 1024;
    const int bh = jv >> 4, tl = jv & 15;
    const float* src = vin + ((size_t)bh * 2048 + tl * 128) * 64;
#pragma unroll
    for (int g = 0; g < 8; ++g) {
      const int f = g * 256 + tid;
      const int r = f >> 4, c4 = f & 15;
      const float4 x = *(const float4*)(src + r * 64 + c4 * 4);
      vld[r][c4 * 4 + 0] = x.x;
      vld[r][c4 * 4 + 1] = x.y;
      vld[r][c4 * 4 + 2] = x.z;
      vld[r][c4 * 4 + 3] = x.w;
    }
    __syncthreads();
    unsigned short* dst = vt_g + (size_t)(bh * 16 + tl) * 8192;
#pragma unroll
    for (int g = 0; g < 4; ++g) {
      const int oc = g * 256 + tid;
      const int d = oc >> 4, cc = oc & 15;
      bf16x8 hv;
#pragma unroll
      for (int j = 0; j < 8; ++j) hv[j] = (short)bf16_rne(vld[cc * 8 + j][d]);
      *(bf16x8*)(dst + (d << 7) + (((cc ^ (d & 15))) << 3)) = hv;
    }
  } else if (jb < 2048) {  // zero d_out: 512 blocks x 2048 float4
    float4* o4 = (float4*)out;
    const size_t b = (size_t)(jb - 1536);
#pragma unroll
    for (int g = 0; g < 8; ++g)
      o4[b * 2048 + g * 256 + tid] = make_float4(0.f, 0.f, 0.f, 0.f);
  } else {  // zero zw (1 MB) + counters (128 B): 65,544 float4s
#pragma unroll
    for (int g = 0; g < 16; ++g) {
      const unsigned i = (unsigned)(jb - 2048) * 4096u + g * 256u + tid;
      if (i < 65544u) wszero[i] = make_float4(0.f, 0.f, 0.f, 0.f);
    }
  }
}

// ====== Phase A: partial (Z,W) accumulated via global atomics; bf16x3 MFMA, BK=64 dbuf ======
// grid 2048: bh = b&31 (XCD-local), ttile = (b>>5)&15, squarter = b>>9 (8 tiles each)
__global__ __launch_bounds__(256, 4) void kl_score_mfma(
    const float* __restrict__ q, const unsigned short* __restrict__ kimg,
    float2* __restrict__ zw) {
  __shared__ __align__(16) unsigned short lbuf[2][8192];  // 2 x 16 KB
  const int b = blockIdx.x;
  const int bh = b & 31;
  const int t0 = ((b >> 5) & 15) * 128;
  const int sq = b >> 9;
  const int tid = threadIdx.x;
  const int lane = tid & 63, w = tid >> 6, quad = lane >> 4, l15 = lane & 15;
  const float* qb = q + (size_t)bh * (2048 * 64) + (size_t)t0 * 64;
  const unsigned short* kb = kimg + (size_t)bh * (32 * 8192);
  const int tg0 = sq * 8;

  {  // q tile -> hi image in lbuf[0], lo image in lbuf[1] (scaled by 0.125*log2e)
#pragma unroll
    for (int g = 0; g < 4; ++g) {
      const int flat = g * 256 + tid;  // 1024 chunks = 128 rows x 8
      const int r = flat >> 3, c = flat & 7;
      const float4 f0 = *(const float4*)(qb + r * 64 + c * 8);
      const float4 f1 = *(const float4*)(qb + r * 64 + c * 8 + 4);
      const float xs[8] = {f0.x, f0.y, f0.z, f0.w, f1.x, f1.y, f1.z, f1.w};
      bf16x8 hv, lv;
#pragma unroll
      for (int j = 0; j < 8; ++j) {
        const float x = xs[j] * SCL_Q;
        const unsigned short h = bf16_rne(x);
        hv[j] = (short)h;
        lv[j] = (short)bf16_rne(x - bf16_to_f(h));
      }
      const int r2 = r & 63, hi2 = r >> 6;
      const int base = hi2 * 4096 + (r2 << 6) + ((c ^ (r2 & 7)) << 3);
      *(bf16x8*)(&lbuf[0][0] + base) = hv;
      *(bf16x8*)(&lbuf[1][0] + base) = lv;
    }
  }
  __syncthreads();

  bf16x8 ah[2][2], al[2][2];  // persistent q A-fragments (wave w: t-rows w*32..w*32+31)
#pragma unroll
  for (int rt = 0; rt < 2; ++rt) {
    const int row = w * 32 + rt * 16 + l15;
#pragma unroll
    for (int kc = 0; kc < 2; ++kc) {
      ah[rt][kc] = ldfrag_k128(&lbuf[0][0], row, kc * 4 + quad);
      al[rt][kc] = ldfrag_k128(&lbuf[1][0], row, kc * 4 + quad);
    }
  }
  __syncthreads();

  stage_img16(kb + (size_t)tg0 * 8192, &lbuf[0][0], lane, w);
  __syncthreads();  // drain tile 0

  float Zf[8], Wf[8];
#pragma unroll
  for (int i = 0; i < 8; ++i) { Zf[i] = 0.f; Wf[i] = 0.f; }

  for (int t = 0; t < 8; ++t) {
    if (t < 7)
      stage_img16(kb + (size_t)(tg0 + t + 1) * 8192, &lbuf[(t + 1) & 1][0], lane, w);
    const unsigned short* cb = &lbuf[t & 1][0];  // [hi 4096 | lo 4096] elems, 64 rows

    f32x4 acc[2][4];
#pragma unroll
    for (int rt = 0; rt < 2; ++rt)
#pragma unroll
      for (int ct = 0; ct < 4; ++ct) acc[rt][ct] = (f32x4){0.f, 0.f, 0.f, 0.f};

#pragma unroll
    for (int ct = 0; ct < 4; ++ct) {
      const int srow = ct * 16 + l15;
      const bf16x8 bh0 = ldfrag_sw(cb, srow, quad);
      const bf16x8 bl0 = ldfrag_sw(cb + 4096, srow, quad);
      const bf16x8 bh1 = ldfrag_sw(cb, srow, 4 + quad);
      const bf16x8 bl1 = ldfrag_sw(cb + 4096, srow, 4 + quad);
#pragma unroll
      for (int rt = 0; rt < 2; ++rt) {
        f32x4 c = acc[rt][ct];
        c = __builtin_amdgcn_mfma_f32_16x16x32_bf16(ah[rt][0], bh0, c, 0, 0, 0);
        c = __builtin_amdgcn_mfma_f32_16x16x32_bf16(al[rt][0], bh0, c, 0, 0, 0);
        c = __builtin_amdgcn_mfma_f32_16x16x32_bf16(ah[rt][0], bl0, c, 0, 0, 0);
        c = __builtin_amdgcn_mfma_f32_16x16x32_bf16(ah[rt][1], bh1, c, 0, 0, 0);
        c = __builtin_amdgcn_mfma_f32_16x16x32_bf16(al[rt][1], bh1, c, 0, 0, 0);
        c = __builtin_amdgcn_mfma_f32_16x16x32_bf16(ah[rt][1], bl1, c, 0, 0, 0);
        acc[rt][ct] = c;
      }
    }

    // no-max epilogue (log2 domain): e = 2^t, W2 += e*t
#pragma unroll
    for (int rt = 0; rt < 2; ++rt)
#pragma unroll
      for (int r = 0; r < 4; ++r) {
        float zp = 0.f, wp = 0.f;
#pragma unroll
        for (int ct = 0; ct < 4; ++ct) {
          const float tt = acc[rt][ct][r];
          const float e = exp2f(tt);
          zp += e;
          wp = fmaf(e, tt, wp);
        }
        Zf[rt * 4 + r] += zp;
        Wf[rt * 4 + r] += wp;
      }
    __syncthreads();  // readers done; drains prefetch of t+1
  }

#pragma unroll
  for (int i = 0; i < 8; ++i) {
    float Zt = Zf[i], Wt = Wf[i];
#pragma unroll
    for (int mask = 1; mask <= 8; mask <<= 1) {
      Zt += __shfl_xor(Zt, mask);
      Wt += __shfl_xor(Wt, mask);
    }
    if (l15 == 0) {
      const int row = t0 + w * 32 + (i >> 2) * 16 + quad * 4 + (i & 3);
      float2* p = &zw[(size_t)bh * 2048 + row];
      atomicAdd(&p->x, Zt);
      atomicAdd(&p->y, Wt);
    }
  }
}

// ====== Phase B: rank-select exact top-614 set (order-invariant: ref scatter ignores order) ======
// grid 64: bh = b>>1, half = b&1; each thread ranks one element against all 2048.
__global__ __launch_bounds__(1024) void topk_kernel(const float2* __restrict__ zw,
                                                    int* __restrict__ topk,
                                                    int* __restrict__ cnt) {
  __shared__ __align__(16) float sv[2048];
  const int bh = blockIdx.x >> 1;
  const int half = blockIdx.x & 1;
  const int tid = threadIdx.x;
  for (int i = tid; i < 2048; i += 1024) {
    const float2 f = zw[(size_t)bh * 2048 + i];
    const double Z = (double)f.x, W = (double)f.y;
    sv[i] = (float)(LN2_D * (W / Z) - log(Z) + LOG_S_D);
  }
  __syncthreads();
  const int e = half * 1024 + tid;
  const float v = sv[e];
  int r = 0;
  for (int j = 0; j < 2048; j += 4) {
    const float4 x = *(const float4*)&sv[j];
    r += (x.x > v) || (x.x == v && (j + 0) < e);
    r += (x.y > v) || (x.y == v && (j + 1) < e);
    r += (x.z > v) || (x.z == v && (j + 2) < e);
    r += (x.w > v) || (x.w == v && (j + 3) < e);
  }
  if (r < U_SEL) topk[bh * U_SEL + atomicAdd(&cnt[bh], 1)] = e;
}

// ====== Phase C: bf16 MFMA attention partials over an S-half (R4 structure) ======
struct __align__(16) SmC {
  unsigned short qs[64 * 64];  // 8 KB
  union {
    struct { unsigned short kt[128 * 64]; unsigned short vt[64 * 128]; } s;  // 32 KB
    float obuf[64 * 64];                                                     // 16 KB
  } u;
  unsigned short ps[4][64 * 40];  // 20 KB, per-wave P [qr][s_local]
  float zred[4][64];              // 1 KB
};

// grid 640: bh = b&31 (XCD-local), rest = b>>5: lt = rest%10, sh = rest/10 (8 tiles each)
__global__ __launch_bounds__(256, 2) void sparse_attn_mfma(
    const float* __restrict__ q, const unsigned short* __restrict__ kimg,
    const unsigned short* __restrict__ vt_g, const int* __restrict__ topk,
    float* __restrict__ po2, float* __restrict__ pz2) {
  __shared__ SmC sm;
  const int b = blockIdx.x;
  const int bh = b & 31;
  const int rest = b >> 5;
  const int lt = rest % LT_N;
  const int sh = rest / LT_N;
  const int l0 = lt * 64;
  const int tid = threadIdx.x;
  const int lane = tid & 63, w = tid >> 6, quad = lane >> 4, l15 = lane & 15;
  const float* qb = q + (size_t)bh * (2048 * 64);
  const unsigned short* kb = kimg + (size_t)bh * (32 * 8192);
  const unsigned short* vtb = vt_g + (size_t)bh * (16 * 8192);
  const int* tkb = topk + bh * U_SEL;

  {  // gather selected q rows -> bf16 * (0.125*log2e), swizzled image
#pragma unroll
    for (int g = 0; g < 2; ++g) {
      const int ch = g * 256 + tid;
      const int r = ch >> 3, c = ch & 7;
      const int l = l0 + r;
      const int row = (l < U_SEL) ? tkb[l] : tkb[0];
      const float4 f0 = *(const float4*)(qb + (size_t)row * 64 + c * 8);
      const float4 f1 = *(const float4*)(qb + (size_t)row * 64 + c * 8 + 4);
      const float xs[8] = {f0.x, f0.y, f0.z, f0.w, f1.x, f1.y, f1.z, f1.w};
      bf16x8 hv;
#pragma unroll
      for (int j = 0; j < 8; ++j) hv[j] = (short)bf16_rne(xs[j] * SCL_Q);
      *(bf16x8*)&sm.qs[(r << 6) + ((c ^ (r & 7)) << 3)] = hv;
    }
  }
  stage_img8(kb + (size_t)(sh * 16) * 8192, sm.u.s.kt, lane, w);
  stage_img8(kb + (size_t)(sh * 16 + 1) * 8192, sm.u.s.kt + 4096, lane, w);
  stage_img16(vtb + (size_t)(sh * 8) * 8192, sm.u.s.vt, lane, w);
  __syncthreads();

  bf16x8 qf[4][2];
#pragma unroll
  for (int nt = 0; nt < 4; ++nt)
#pragma unroll
    for (int kc = 0; kc < 2; ++kc)
      qf[nt][kc] = ldfrag_sw(sm.qs, nt * 16 + l15, kc * 4 + quad);

  float zrun[4] = {0.f, 0.f, 0.f, 0.f};
  f32x4 oacc[4][4];
#pragma unroll
  for (int a = 0; a < 4; ++a)
#pragma unroll
    for (int b2 = 0; b2 < 4; ++b2) oacc[a][b2] = (f32x4){0.f, 0.f, 0.f, 0.f};

  for (int st = 0; st < 8; ++st) {
    // S^T = K·q^T : C[m=s][n=qr]; wave w owns s in [st*128 + w*32, +32)
    f32x4 sacc[2][4];
#pragma unroll
    for (int mt = 0; mt < 2; ++mt)
#pragma unroll
      for (int nt = 0; nt < 4; ++nt) {
        const int arow = w * 32 + mt * 16 + l15;
        const bf16x8 a0 = ldfrag_k128(sm.u.s.kt, arow, quad);
        const bf16x8 a1 = ldfrag_k128(sm.u.s.kt, arow, 4 + quad);
        f32x4 c = (f32x4){0.f, 0.f, 0.f, 0.f};
        c = __builtin_amdgcn_mfma_f32_16x16x32_bf16(a0, qf[nt][0], c, 0, 0, 0);
        c = __builtin_amdgcn_mfma_f32_16x16x32_bf16(a1, qf[nt][1], c, 0, 0, 0);
        sacc[mt][nt] = c;
      }

    // no-max: p = 2^t; per-thread Z partials; P -> per-wave LDS
#pragma unroll
    for (int nt = 0; nt < 4; ++nt) {
      float zl = 0.f;
#pragma unroll
      for (int mt = 0; mt < 2; ++mt) {
        bf16x4 pw;
#pragma unroll
        for (int r = 0; r < 4; ++r) {
          const float p = exp2f(sacc[mt][nt][r]);
          zl += p;
          pw[r] = (short)bf16_rne(p);
        }
        *(bf16x4*)&sm.ps[w][(nt * 16 + l15) * 40 + mt * 16 + quad * 4] = pw;
      }
      zrun[nt] += zl;
    }

    // PV: O[qr][d] += P[qr][s]·V^T[d][s] (own-wave ps: in-order DS pipe, no barrier)
    {
      bf16x8 vbf[4];
      const int cc = w * 4 + quad;
#pragma unroll
      for (int dt = 0; dt < 4; ++dt) {
        const int d = dt * 16 + l15;
        vbf[dt] = *(const bf16x8*)&sm.u.s.vt[(d << 7) + ((cc ^ (d & 15)) << 3)];
      }
#pragma unroll
      for (int mtq = 0; mtq < 4; ++mtq) {
        const bf16x8 pa = *(const bf16x8*)&sm.ps[w][(mtq * 16 + l15) * 40 + quad * 8];
#pragma unroll
        for (int dt = 0; dt < 4; ++dt)
          oacc[mtq][dt] = __builtin_amdgcn_mfma_f32_16x16x32_bf16(pa, vbf[dt], oacc[mtq][dt], 0, 0, 0);
      }
    }
    __syncthreads();
    if (st < 7) {
      stage_img8(kb + (size_t)(sh * 16 + 2 * st + 2) * 8192, sm.u.s.kt, lane, w);
      stage_img8(kb + (size_t)(sh * 16 + 2 * st + 3) * 8192, sm.u.s.kt + 4096, lane, w);
      stage_img16(vtb + (size_t)(sh * 8 + st + 1) * 8192, sm.u.s.vt, lane, w);
      __syncthreads();
    }
  }

  // in-block merge: Z over quads (shfl) + waves; O over waves (LDS atomics); store partials
#pragma unroll
  for (int nt = 0; nt < 4; ++nt) {
    float z = zrun[nt];
    z += __shfl_xor(z, 16);
    z += __shfl_xor(z, 32);
    if (quad == 0) sm.zred[w][nt * 16 + l15] = z;
  }
  __syncthreads();  // kt/vt reads done -> obuf may overwrite
  for (int i = tid; i < 64 * 64; i += 256) sm.u.obuf[i] = 0.f;
  __syncthreads();
#pragma unroll
  for (int mtq = 0; mtq < 4; ++mtq)
#pragma unroll
    for (int r = 0; r < 4; ++r) {
      const int qr = mtq * 16 + quad * 4 + r;
#pragma unroll
      for (int dt = 0; dt < 4; ++dt)
        atomicAdd(&sm.u.obuf[qr * 64 + dt * 16 + l15], oacc[mtq][dt][r]);
    }
  __syncthreads();
  {
    const int base = (bh * LT_N + lt) * 2 + sh;
    float4* po4 = (float4*)(po2 + (size_t)base * 4096);
    const float4* ob4 = (const float4*)sm.u.obuf;
#pragma unroll
    for (int g = 0; g < 4; ++g) po4[g * 256 + tid] = ob4[g * 256 + tid];
    if (tid < 64)
      pz2[(size_t)base * 64 + tid] =
          sm.zred[0][tid] + sm.zred[1][tid] + sm.zred[2][tid] + sm.zred[3][tid];
  }
}

// ====== merge: out[tkb[l]] = (O0+O1)/(Z0+Z1) ======
// grid 320: bh = b%32, lt = b/32
__global__ __launch_bounds__(256) void merge_kernel(
    const float* __restrict__ po2, const float* __restrict__ pz2,
    const int* __restrict__ topk, float* __restrict__ out) {
  __shared__ float zs[64];
  const int b = blockIdx.x;
  const int bh = b & 31;
  const int lt = b >> 5;
  const int tid = threadIdx.x;
  const int base = (bh * LT_N + lt) * 2;
  const float4* p0 = (const float4*)(po2 + (size_t)base * 4096);
  const float4* p1 = (const float4*)(po2 + (size_t)(base + 1) * 4096);
  const int* tkb = topk + bh * U_SEL;
  if (tid < 64) zs[tid] = pz2[(size_t)base * 64 + tid] + pz2[(size_t)(base + 1) * 64 + tid];
  __syncthreads();
#pragma unroll
  for (int g = 0; g < 4; ++g) {
    const int i = g * 256 + tid;  // float4 index; qr = i>>4, d4 = i&15
    const int qr = i >> 4;
    const int l = lt * 64 + qr;
    if (l < U_SEL) {
      const int row = tkb[l];
      const float inv = 1.0f / zs[qr];
      const float4 a = p0[i], c = p1[i];
      float4 o;
      o.x = (a.x + c.x) * inv;
      o.y = (a.y + c.y) * inv;
      o.z = (a.z + c.z) * inv;
      o.w = (a.w + c.w) * inv;
      ((float4*)out)[((size_t)bh * 2048 + row) * 16 + (i & 15)] = o;
    }
  }
}

extern "C" void kernel_launch(void* const* d_in, const int* in_sizes, int n_in,
                              void* d_out, int out_size, void* d_ws, size_t ws_size,
                              hipStream_t stream) {
  const float* q = (const float*)d_in[0];
  const float* k = (const float*)d_in[1];
  const float* v = (const float*)d_in[2];
  float* out = (float*)d_out;
  char* ws = (char*)d_ws;
  float2* zw = (float2*)(ws + WS_ZW);
  int* cnt = (int*)(ws + WS_CNT);
  int* topk = (int*)(ws + WS_TOPK);
  float* po2 = (float*)(ws + WS_PO);
  float* pz2 = (float*)(ws + WS_PZ);
  unsigned short* kimg = (unsigned short*)(ws + WS_KIMG);
  unsigned short* vt_g = (unsigned short*)(ws + WS_VT);

  convert_kernel<<<dim3(2065), dim3(256), 0, stream>>>(k, v, kimg, vt_g, out, (float4*)ws);
  kl_score_mfma<<<dim3(2048), dim3(256), 0, stream>>>(q, kimg, zw);
  topk_kernel<<<dim3(64), dim3(1024), 0, stream>>>(zw, topk, cnt);
  sparse_attn_mfma<<<dim3(640), dim3(256), 0, stream>>>(q, kimg, vt_g, topk, po2, pz2);
  merge_kernel<<<dim3(320), dim3(256), 0, stream>>>(po2, pz2, topk, out);
}

// Round 7
// 330.468 us; speedup vs baseline: 10.4249x; 2.7325x over previous
//
#include <hip/hip_runtime.h>
#include <math.h>

#define T_DIM 2048
#define S_DIM 2048
#define D_DIM 64
#define BH_DIM 32
#define U_SEL 614
#define LT_N 10
#define LOG_S_D 7.624618986159398
#define LOG2E_F 1.4426950408889634f
#define LN2_D 0.6931471805599453
#define SCL_Q (0.125f * LOG2E_F)  // q scale folded with log2e: scores in log2 domain

// ---- workspace layout (bytes) ----
#define WS_ZW 0u               // float2[32][2048] = 1,048,576
#define WS_CNT 1048576u        // int[32] = 128  (zeroed with zw)
#define WS_TOPK 1048704u       // int[32][614] = 78,592
#define WS_PO 1127424u         // float[640][4096] = 10,485,760
#define WS_PZ 11613184u        // float[640][64] = 163,840
#define WS_KIMG 11777024u      // 16,777,216
#define WS_VT 28554240u        // 8,388,608  (end ~35.2 MB)

typedef __attribute__((ext_vector_type(8))) short bf16x8;
typedef __attribute__((ext_vector_type(4))) short bf16x4;
typedef __attribute__((ext_vector_type(4))) float f32x4;

__device__ __forceinline__ unsigned short bf16_rne(float x) {
  unsigned u = __float_as_uint(x);
  u += 0x7FFF + ((u >> 16) & 1);
  return (unsigned short)(u >> 16);
}
__device__ __forceinline__ float bf16_to_f(unsigned short h) {
  return __uint_as_float(((unsigned)h) << 16);
}

#define GLD_LDS16(g, l)                                                        \
  __builtin_amdgcn_global_load_lds(                                            \
      (const __attribute__((address_space(1))) unsigned int*)(const void*)(g), \
      (__attribute__((address_space(3))) unsigned int*)(void*)(l), 16, 0, 0)

// stage 16 KB image: 4 waves x 4 instr x 64 lanes x 16 B
__device__ __forceinline__ void stage_img16(const unsigned short* __restrict__ g,
                                            unsigned short* l, int lane, int w) {
#pragma unroll
  for (int it = 0; it < 4; ++it) {
    const int chunk = it * 4 + w;
    GLD_LDS16((const char*)g + chunk * 1024 + lane * 16, (char*)l + chunk * 1024);
  }
}
// stage 8 KB image
__device__ __forceinline__ void stage_img8(const unsigned short* __restrict__ g,
                                           unsigned short* l, int lane, int w) {
#pragma unroll
  for (int it = 0; it < 2; ++it) {
    const int chunk = it * 4 + w;
    GLD_LDS16((const char*)g + chunk * 1024 + lane * 16, (char*)l + chunk * 1024);
  }
}

// swizzled image, 64-wide rows: element (r,d) at r*64 + ((d>>3)^(r&7))*8 + (d&7)
__device__ __forceinline__ bf16x8 ldfrag_sw(const unsigned short* buf, int row, int chunk) {
  return *(const bf16x8*)(buf + (row << 6) + (((chunk) ^ (row & 7)) << 3));
}
// two stacked 64-row images (rows 0..127)
__device__ __forceinline__ bf16x8 ldfrag_k128(const unsigned short* buf, int row, int chunk) {
  return *(const bf16x8*)(buf + ((row >> 6) << 12) + ((row & 63) << 6) +
                          (((chunk) ^ (row & 7)) << 3));
}

// ====== convert: K -> 64-row tiles [hi 8KB | lo 8KB] swizzled; V -> V^T images;
//        zero(out); zero(zw + counters) ======
__global__ __launch_bounds__(256) void convert_kernel(
    const float* __restrict__ kin, const float* __restrict__ vin,
    unsigned short* __restrict__ kimg, unsigned short* __restrict__ vt_g,
    float* __restrict__ out, float4* __restrict__ wszero) {
  __shared__ float vld[128][65];
  const int jb = blockIdx.x;
  const int tid = threadIdx.x;
  if (jb < 1024) {  // K: 32 bh x 32 tiles of 64 rows
    const int bh = jb >> 5, tl = jb & 31;
    const float* src = kin + ((size_t)bh * 2048 + tl * 64) * 64;
    unsigned short* dst = kimg + (size_t)(bh * 32 + tl) * 8192;
#pragma unroll
    for (int g = 0; g < 2; ++g) {
      const int flat = g * 256 + tid;  // 512 chunks = 64 rows x 8
      const int r = flat >> 3, c = flat & 7;
      const float4 f0 = *(const float4*)(src + r * 64 + c * 8);
      const float4 f1 = *(const float4*)(src + r * 64 + c * 8 + 4);
      const float xs[8] = {f0.x, f0.y, f0.z, f0.w, f1.x, f1.y, f1.z, f1.w};
      bf16x8 hv, lv;
#pragma unroll
      for (int j = 0; j < 8; ++j) {
        const unsigned short h = bf16_rne(xs[j]);
        hv[j] = (short)h;
        lv[j] = (short)bf16_rne(xs[j] - bf16_to_f(h));
      }
      const int base = (r << 6) + ((c ^ (r & 7)) << 3);
      *(bf16x8*)(dst + base) = hv;
      *(bf16x8*)(dst + 4096 + base) = lv;
    }
  } else if (jb < 1536) {  // V^T: [64 d][128 s] bf16, chunk ^ (d&15)
    const int jv = jb - 1024;
    const int bh = jv >> 4, tl = jv & 15;
    const float* src = vin + ((size_t)bh * 2048 + tl * 128) * 64;
#pragma unroll
    for (int g = 0; g < 8; ++g) {
      const int f = g * 256 + tid;
      const int r = f >> 4, c4 = f & 15;
      const float4 x = *(const float4*)(src + r * 64 + c4 * 4);
      vld[r][c4 * 4 + 0] = x.x;
      vld[r][c4 * 4 + 1] = x.y;
      vld[r][c4 * 4 + 2] = x.z;
      vld[r][c4 * 4 + 3] = x.w;
    }
    __syncthreads();
    unsigned short* dst = vt_g + (size_t)(bh * 16 + tl) * 8192;
#pragma unroll
    for (int g = 0; g < 4; ++g) {
      const int oc = g * 256 + tid;
      const int d = oc >> 4, cc = oc & 15;
      bf16x8 hv;
#pragma unroll
      for (int j = 0; j < 8; ++j) hv[j] = (short)bf16_rne(vld[cc * 8 + j][d]);
      *(bf16x8*)(dst + (d << 7) + (((cc ^ (d & 15))) << 3)) = hv;
    }
  } else if (jb < 2048) {  // zero d_out: 512 blocks x 2048 float4
    float4* o4 = (float4*)out;
    const size_t b = (size_t)(jb - 1536);
#pragma unroll
    for (int g = 0; g < 8; ++g)
      o4[b * 2048 + g * 256 + tid] = make_float4(0.f, 0.f, 0.f, 0.f);
  } else {  // zero zw (1 MB) + counters (128 B): 65,544 float4s
#pragma unroll
    for (int g = 0; g < 16; ++g) {
      const unsigned i = (unsigned)(jb - 2048) * 4096u + g * 256u + tid;
      if (i < 65544u) wszero[i] = make_float4(0.f, 0.f, 0.f, 0.f);
    }
  }
}

// ====== Phase A: partial (Z,W) accumulated via global atomics; bf16x3 MFMA, BK=64 dbuf ======
// grid 2048: bh = b&31 (XCD-local), ttile = (b>>5)&15, squarter = b>>9 (8 tiles each)
__global__ __launch_bounds__(256, 4) void kl_score_mfma(
    const float* __restrict__ q, const unsigned short* __restrict__ kimg,
    float2* __restrict__ zw) {
  __shared__ __align__(16) unsigned short lbuf[2][8192];  // 2 x 16 KB
  const int b = blockIdx.x;
  const int bh = b & 31;
  const int t0 = ((b >> 5) & 15) * 128;
  const int sq = b >> 9;
  const int tid = threadIdx.x;
  const int lane = tid & 63, w = tid >> 6, quad = lane >> 4, l15 = lane & 15;
  const float* qb = q + (size_t)bh * (2048 * 64) + (size_t)t0 * 64;
  const unsigned short* kb = kimg + (size_t)bh * (32 * 8192);
  const int tg0 = sq * 8;

  {  // q tile -> hi image in lbuf[0], lo image in lbuf[1] (scaled by 0.125*log2e)
#pragma unroll
    for (int g = 0; g < 4; ++g) {
      const int flat = g * 256 + tid;  // 1024 chunks = 128 rows x 8
      const int r = flat >> 3, c = flat & 7;
      const float4 f0 = *(const float4*)(qb + r * 64 + c * 8);
      const float4 f1 = *(const float4*)(qb + r * 64 + c * 8 + 4);
      const float xs[8] = {f0.x, f0.y, f0.z, f0.w, f1.x, f1.y, f1.z, f1.w};
      bf16x8 hv, lv;
#pragma unroll
      for (int j = 0; j < 8; ++j) {
        const float x = xs[j] * SCL_Q;
        const unsigned short h = bf16_rne(x);
        hv[j] = (short)h;
        lv[j] = (short)bf16_rne(x - bf16_to_f(h));
      }
      const int r2 = r & 63, hi2 = r >> 6;
      const int base = hi2 * 4096 + (r2 << 6) + ((c ^ (r2 & 7)) << 3);
      *(bf16x8*)(&lbuf[0][0] + base) = hv;
      *(bf16x8*)(&lbuf[1][0] + base) = lv;
    }
  }
  __syncthreads();

  bf16x8 ah[2][2], al[2][2];  // persistent q A-fragments (wave w: t-rows w*32..w*32+31)
#pragma unroll
  for (int rt = 0; rt < 2; ++rt) {
    const int row = w * 32 + rt * 16 + l15;
#pragma unroll
    for (int kc = 0; kc < 2; ++kc) {
      ah[rt][kc] = ldfrag_k128(&lbuf[0][0], row, kc * 4 + quad);
      al[rt][kc] = ldfrag_k128(&lbuf[1][0], row, kc * 4 + quad);
    }
  }
  __syncthreads();

  stage_img16(kb + (size_t)tg0 * 8192, &lbuf[0][0], lane, w);
  __syncthreads();  // drain tile 0

  float Zf[8], Wf[8];
#pragma unroll
  for (int i = 0; i < 8; ++i) { Zf[i] = 0.f; Wf[i] = 0.f; }

  // unroll 1: trip-8 constant loop MUST stay rolled — full unroll replicates the
  // prefetch/acc live ranges 8x, blows the (256,4) 128-VGPR cap, and spills
  // ~2 KB/thread to scratch (R6: 2.16 GB HBM traffic, 640 us).
#pragma unroll 1
  for (int t = 0; t < 8; ++t) {
    if (t < 7)
      stage_img16(kb + (size_t)(tg0 + t + 1) * 8192, &lbuf[(t + 1) & 1][0], lane, w);
    const unsigned short* cb = &lbuf[t & 1][0];  // [hi 4096 | lo 4096] elems, 64 rows

    f32x4 acc[2][4];
#pragma unroll
    for (int rt = 0; rt < 2; ++rt)
#pragma unroll
      for (int ct = 0; ct < 4; ++ct) acc[rt][ct] = (f32x4){0.f, 0.f, 0.f, 0.f};

#pragma unroll
    for (int ct = 0; ct < 4; ++ct) {
      const int srow = ct * 16 + l15;
      const bf16x8 bh0 = ldfrag_sw(cb, srow, quad);
      const bf16x8 bl0 = ldfrag_sw(cb + 4096, srow, quad);
      const bf16x8 bh1 = ldfrag_sw(cb, srow, 4 + quad);
      const bf16x8 bl1 = ldfrag_sw(cb + 4096, srow, 4 + quad);
#pragma unroll
      for (int rt = 0; rt < 2; ++rt) {
        f32x4 c = acc[rt][ct];
        c = __builtin_amdgcn_mfma_f32_16x16x32_bf16(ah[rt][0], bh0, c, 0, 0, 0);
        c = __builtin_amdgcn_mfma_f32_16x16x32_bf16(al[rt][0], bh0, c, 0, 0, 0);
        c = __builtin_amdgcn_mfma_f32_16x16x32_bf16(ah[rt][0], bl0, c, 0, 0, 0);
        c = __builtin_amdgcn_mfma_f32_16x16x32_bf16(ah[rt][1], bh1, c, 0, 0, 0);
        c = __builtin_amdgcn_mfma_f32_16x16x32_bf16(al[rt][1], bh1, c, 0, 0, 0);
        c = __builtin_amdgcn_mfma_f32_16x16x32_bf16(ah[rt][1], bl1, c, 0, 0, 0);
        acc[rt][ct] = c;
      }
    }

    // no-max epilogue (log2 domain): e = 2^t, W2 += e*t
#pragma unroll
    for (int rt = 0; rt < 2; ++rt)
#pragma unroll
      for (int r = 0; r < 4; ++r) {
        float zp = 0.f, wp = 0.f;
#pragma unroll
        for (int ct = 0; ct < 4; ++ct) {
          const float tt = acc[rt][ct][r];
          const float e = exp2f(tt);
          zp += e;
          wp = fmaf(e, tt, wp);
        }
        Zf[rt * 4 + r] += zp;
        Wf[rt * 4 + r] += wp;
      }
    __syncthreads();  // readers done; drains prefetch of t+1
  }

#pragma unroll
  for (int i = 0; i < 8; ++i) {
    float Zt = Zf[i], Wt = Wf[i];
#pragma unroll
    for (int mask = 1; mask <= 8; mask <<= 1) {
      Zt += __shfl_xor(Zt, mask);
      Wt += __shfl_xor(Wt, mask);
    }
    if (l15 == 0) {
      const int row = t0 + w * 32 + (i >> 2) * 16 + quad * 4 + (i & 3);
      float2* p = &zw[(size_t)bh * 2048 + row];
      atomicAdd(&p->x, Zt);
      atomicAdd(&p->y, Wt);
    }
  }
}

// ====== Phase B: rank-select exact top-614 set (order-invariant: ref scatter ignores order) ======
// grid 64: bh = b>>1, half = b&1; each thread ranks one element against all 2048.
__global__ __launch_bounds__(1024) void topk_kernel(const float2* __restrict__ zw,
                                                    int* __restrict__ topk,
                                                    int* __restrict__ cnt) {
  __shared__ __align__(16) float sv[2048];
  const int bh = blockIdx.x >> 1;
  const int half = blockIdx.x & 1;
  const int tid = threadIdx.x;
  for (int i = tid; i < 2048; i += 1024) {
    const float2 f = zw[(size_t)bh * 2048 + i];
    const double Z = (double)f.x, W = (double)f.y;
    sv[i] = (float)(LN2_D * (W / Z) - log(Z) + LOG_S_D);
  }
  __syncthreads();
  const int e = half * 1024 + tid;
  const float v = sv[e];
  int r = 0;
#pragma unroll 1
  for (int j = 0; j < 2048; j += 4) {
    const float4 x = *(const float4*)&sv[j];
    r += (x.x > v) || (x.x == v && (j + 0) < e);
    r += (x.y > v) || (x.y == v && (j + 1) < e);
    r += (x.z > v) || (x.z == v && (j + 2) < e);
    r += (x.w > v) || (x.w == v && (j + 3) < e);
  }
  if (r < U_SEL) topk[bh * U_SEL + atomicAdd(&cnt[bh], 1)] = e;
}

// ====== Phase C: bf16 MFMA attention partials over an S-half (R4 structure) ======
struct __align__(16) SmC {
  unsigned short qs[64 * 64];  // 8 KB
  union {
    struct { unsigned short kt[128 * 64]; unsigned short vt[64 * 128]; } s;  // 32 KB
    float obuf[64 * 64];                                                     // 16 KB
  } u;
  unsigned short ps[4][64 * 40];  // 20 KB, per-wave P [qr][s_local]
  float zred[4][64];              // 1 KB
};

// grid 640: bh = b&31 (XCD-local), rest = b>>5: lt = rest%10, sh = rest/10 (8 tiles each)
__global__ __launch_bounds__(256, 2) void sparse_attn_mfma(
    const float* __restrict__ q, const unsigned short* __restrict__ kimg,
    const unsigned short* __restrict__ vt_g, const int* __restrict__ topk,
    float* __restrict__ po2, float* __restrict__ pz2) {
  __shared__ SmC sm;
  const int b = blockIdx.x;
  const int bh = b & 31;
  const int rest = b >> 5;
  const int lt = rest % LT_N;
  const int sh = rest / LT_N;
  const int l0 = lt * 64;
  const int tid = threadIdx.x;
  const int lane = tid & 63, w = tid >> 6, quad = lane >> 4, l15 = lane & 15;
  const float* qb = q + (size_t)bh * (2048 * 64);
  const unsigned short* kb = kimg + (size_t)bh * (32 * 8192);
  const unsigned short* vtb = vt_g + (size_t)bh * (16 * 8192);
  const int* tkb = topk + bh * U_SEL;

  {  // gather selected q rows -> bf16 * (0.125*log2e), swizzled image
#pragma unroll
    for (int g = 0; g < 2; ++g) {
      const int ch = g * 256 + tid;
      const int r = ch >> 3, c = ch & 7;
      const int l = l0 + r;
      const int row = (l < U_SEL) ? tkb[l] : tkb[0];
      const float4 f0 = *(const float4*)(qb + (size_t)row * 64 + c * 8);
      const float4 f1 = *(const float4*)(qb + (size_t)row * 64 + c * 8 + 4);
      const float xs[8] = {f0.x, f0.y, f0.z, f0.w, f1.x, f1.y, f1.z, f1.w};
      bf16x8 hv;
#pragma unroll
      for (int j = 0; j < 8; ++j) hv[j] = (short)bf16_rne(xs[j] * SCL_Q);
      *(bf16x8*)&sm.qs[(r << 6) + ((c ^ (r & 7)) << 3)] = hv;
    }
  }
  stage_img8(kb + (size_t)(sh * 16) * 8192, sm.u.s.kt, lane, w);
  stage_img8(kb + (size_t)(sh * 16 + 1) * 8192, sm.u.s.kt + 4096, lane, w);
  stage_img16(vtb + (size_t)(sh * 8) * 8192, sm.u.s.vt, lane, w);
  __syncthreads();

  bf16x8 qf[4][2];
#pragma unroll
  for (int nt = 0; nt < 4; ++nt)
#pragma unroll
    for (int kc = 0; kc < 2; ++kc)
      qf[nt][kc] = ldfrag_sw(sm.qs, nt * 16 + l15, kc * 4 + quad);

  float zrun[4] = {0.f, 0.f, 0.f, 0.f};
  f32x4 oacc[4][4];
#pragma unroll
  for (int a = 0; a < 4; ++a)
#pragma unroll
    for (int b2 = 0; b2 < 4; ++b2) oacc[a][b2] = (f32x4){0.f, 0.f, 0.f, 0.f};

  // unroll 1: same spill hazard as kl_score's K-loop (see comment there)
#pragma unroll 1
  for (int st = 0; st < 8; ++st) {
    // S^T = K·q^T : C[m=s][n=qr]; wave w owns s in [st*128 + w*32, +32)
    f32x4 sacc[2][4];
#pragma unroll
    for (int mt = 0; mt < 2; ++mt)
#pragma unroll
      for (int nt = 0; nt < 4; ++nt) {
        const int arow = w * 32 + mt * 16 + l15;
        const bf16x8 a0 = ldfrag_k128(sm.u.s.kt, arow, quad);
        const bf16x8 a1 = ldfrag_k128(sm.u.s.kt, arow, 4 + quad);
        f32x4 c = (f32x4){0.f, 0.f, 0.f, 0.f};
        c = __builtin_amdgcn_mfma_f32_16x16x32_bf16(a0, qf[nt][0], c, 0, 0, 0);
        c = __builtin_amdgcn_mfma_f32_16x16x32_bf16(a1, qf[nt][1], c, 0, 0, 0);
        sacc[mt][nt] = c;
      }

    // no-max: p = 2^t; per-thread Z partials; P -> per-wave LDS
#pragma unroll
    for (int nt = 0; nt < 4; ++nt) {
      float zl = 0.f;
#pragma unroll
      for (int mt = 0; mt < 2; ++mt) {
        bf16x4 pw;
#pragma unroll
        for (int r = 0; r < 4; ++r) {
          const float p = exp2f(sacc[mt][nt][r]);
          zl += p;
          pw[r] = (short)bf16_rne(p);
        }
        *(bf16x4*)&sm.ps[w][(nt * 16 + l15) * 40 + mt * 16 + quad * 4] = pw;
      }
      zrun[nt] += zl;
    }

    // PV: O[qr][d] += P[qr][s]·V^T[d][s] (own-wave ps: in-order DS pipe, no barrier)
    {
      bf16x8 vbf[4];
      const int cc = w * 4 + quad;
#pragma unroll
      for (int dt = 0; dt < 4; ++dt) {
        const int d = dt * 16 + l15;
        vbf[dt] = *(const bf16x8*)&sm.u.s.vt[(d << 7) + ((cc ^ (d & 15)) << 3)];
      }
#pragma unroll
      for (int mtq = 0; mtq < 4; ++mtq) {
        const bf16x8 pa = *(const bf16x8*)&sm.ps[w][(mtq * 16 + l15) * 40 + quad * 8];
#pragma unroll
        for (int dt = 0; dt < 4; ++dt)
          oacc[mtq][dt] = __builtin_amdgcn_mfma_f32_16x16x32_bf16(pa, vbf[dt], oacc[mtq][dt], 0, 0, 0);
      }
    }
    __syncthreads();
    if (st < 7) {
      stage_img8(kb + (size_t)(sh * 16 + 2 * st + 2) * 8192, sm.u.s.kt, lane, w);
      stage_img8(kb + (size_t)(sh * 16 + 2 * st + 3) * 8192, sm.u.s.kt + 4096, lane, w);
      stage_img16(vtb + (size_t)(sh * 8 + st + 1) * 8192, sm.u.s.vt, lane, w);
      __syncthreads();
    }
  }

  // in-block merge: Z over quads (shfl) + waves; O over waves (LDS atomics); store partials
#pragma unroll
  for (int nt = 0; nt < 4; ++nt) {
    float z = zrun[nt];
    z += __shfl_xor(z, 16);
    z += __shfl_xor(z, 32);
    if (quad == 0) sm.zred[w][nt * 16 + l15] = z;
  }
  __syncthreads();  // kt/vt reads done -> obuf may overwrite
  for (int i = tid; i < 64 * 64; i += 256) sm.u.obuf[i] = 0.f;
  __syncthreads();
#pragma unroll
  for (int mtq = 0; mtq < 4; ++mtq)
#pragma unroll
    for (int r = 0; r < 4; ++r) {
      const int qr = mtq * 16 + quad * 4 + r;
#pragma unroll
      for (int dt = 0; dt < 4; ++dt)
        atomicAdd(&sm.u.obuf[qr * 64 + dt * 16 + l15], oacc[mtq][dt][r]);
    }
  __syncthreads();
  {
    const int base = (bh * LT_N + lt) * 2 + sh;
    float4* po4 = (float4*)(po2 + (size_t)base * 4096);
    const float4* ob4 = (const float4*)sm.u.obuf;
#pragma unroll
    for (int g = 0; g < 4; ++g) po4[g * 256 + tid] = ob4[g * 256 + tid];
    if (tid < 64)
      pz2[(size_t)base * 64 + tid] =
          sm.zred[0][tid] + sm.zred[1][tid] + sm.zred[2][tid] + sm.zred[3][tid];
  }
}

// ====== merge: out[tkb[l]] = (O0+O1)/(Z0+Z1) ======
// grid 320: bh = b%32, lt = b/32
__global__ __launch_bounds__(256) void merge_kernel(
    const float* __restrict__ po2, const float* __restrict__ pz2,
    const int* __restrict__ topk, float* __restrict__ out) {
  __shared__ float zs[64];
  const int b = blockIdx.x;
  const int bh = b & 31;
  const int lt = b >> 5;
  const int tid = threadIdx.x;
  const int base = (bh * LT_N + lt) * 2;
  const float4* p0 = (const float4*)(po2 + (size_t)base * 4096);
  const float4* p1 = (const float4*)(po2 + (size_t)(base + 1) * 4096);
  const int* tkb = topk + bh * U_SEL;
  if (tid < 64) zs[tid] = pz2[(size_t)base * 64 + tid] + pz2[(size_t)(base + 1) * 64 + tid];
  __syncthreads();
#pragma unroll
  for (int g = 0; g < 4; ++g) {
    const int i = g * 256 + tid;  // float4 index; qr = i>>4, d4 = i&15
    const int qr = i >> 4;
    const int l = lt * 64 + qr;
    if (l < U_SEL) {
      const int row = tkb[l];
      const float inv = 1.0f / zs[qr];
      const float4 a = p0[i], c = p1[i];
      float4 o;
      o.x = (a.x + c.x) * inv;
      o.y = (a.y + c.y) * inv;
      o.z = (a.z + c.z) * inv;
      o.w = (a.w + c.w) * inv;
      ((float4*)out)[((size_t)bh * 2048 + row) * 16 + (i & 15)] = o;
    }
  }
}

extern "C" void kernel_launch(void* const* d_in, const int* in_sizes, int n_in,
                              void* d_out, int out_size, void* d_ws, size_t ws_size,
                              hipStream_t stream) {
  const float* q = (const float*)d_in[0];
  const float* k = (const float*)d_in[1];
  const float* v = (const float*)d_in[2];
  float* out = (float*)d_out;
  char* ws = (char*)d_ws;
  float2* zw = (float2*)(ws + WS_ZW);
  int* cnt = (int*)(ws + WS_CNT);
  int* topk = (int*)(ws + WS_TOPK);
  float* po2 = (float*)(ws + WS_PO);
  float* pz2 = (float*)(ws + WS_PZ);
  unsigned short* kimg = (unsigned short*)(ws + WS_KIMG);
  unsigned short* vt_g = (unsigned short*)(ws + WS_VT);

  convert_kernel<<<dim3(2065), dim3(256), 0, stream>>>(k, v, kimg, vt_g, out, (float4*)ws);
  kl_score_mfma<<<dim3(2048), dim3(256), 0, stream>>>(q, kimg, zw);
  topk_kernel<<<dim3(64), dim3(1024), 0, stream>>>(zw, topk, cnt);
  sparse_attn_mfma<<<dim3(640), dim3(256), 0, stream>>>(q, kimg, vt_g, topk, po2, pz2);
  merge_kernel<<<dim3(320), dim3(256), 0, stream>>>(po2, pz2, topk, out);
}

// Round 8
// 271.008 us; speedup vs baseline: 12.7121x; 1.2194x over previous
//
#include <hip/hip_runtime.h>
#include <math.h>

#define T_DIM 2048
#define S_DIM 2048
#define D_DIM 64
#define BH_DIM 32
#define U_SEL 614
#define LT_N 10
#define SQ_N 4
#define LOG_S_D 7.624618986159398
#define LOG2E_F 1.4426950408889634f
#define LN2_D 0.6931471805599453
#define SCL_Q (0.125f * LOG2E_F)  // q scale folded with log2e: scores in log2 domain

// ---- workspace layout (bytes), total ~30.2 MB ----
#define WS_ZW 0u               // float2[32][2048] = 1,048,576
#define WS_CNT 1048576u        // int[32] = 128 (zeroed with zw)
#define WS_TOPK 1048704u       // int[32][614] = 78,592 (pad to 1,127,424)
#define WS_PO 1127424u         // float[32][10][64][64] = 5,242,880 (atomic-accumulated)
#define WS_PZ 6370304u         // float[32][10][64] = 81,920 (atomic-accumulated)
#define WS_KIMG 6452224u       // 16,777,216
#define WS_VT 23229440u        // 8,388,608 (V^T in 64-s tiles)

typedef __attribute__((ext_vector_type(8))) short bf16x8;
typedef __attribute__((ext_vector_type(4))) short bf16x4;
typedef __attribute__((ext_vector_type(4))) float f32x4;

__device__ __forceinline__ unsigned short bf16_rne(float x) {
  unsigned u = __float_as_uint(x);
  u += 0x7FFF + ((u >> 16) & 1);
  return (unsigned short)(u >> 16);
}
__device__ __forceinline__ float bf16_to_f(unsigned short h) {
  return __uint_as_float(((unsigned)h) << 16);
}

#define GLD_LDS16(g, l)                                                        \
  __builtin_amdgcn_global_load_lds(                                            \
      (const __attribute__((address_space(1))) unsigned int*)(const void*)(g), \
      (__attribute__((address_space(3))) unsigned int*)(void*)(l), 16, 0, 0)

// stage 16 KB image: 4 waves x 4 instr x 64 lanes x 16 B
__device__ __forceinline__ void stage_img16(const unsigned short* __restrict__ g,
                                            unsigned short* l, int lane, int w) {
#pragma unroll
  for (int it = 0; it < 4; ++it) {
    const int chunk = it * 4 + w;
    GLD_LDS16((const char*)g + chunk * 1024 + lane * 16, (char*)l + chunk * 1024);
  }
}
// stage 8 KB image
__device__ __forceinline__ void stage_img8(const unsigned short* __restrict__ g,
                                           unsigned short* l, int lane, int w) {
#pragma unroll
  for (int it = 0; it < 2; ++it) {
    const int chunk = it * 4 + w;
    GLD_LDS16((const char*)g + chunk * 1024 + lane * 16, (char*)l + chunk * 1024);
  }
}

// swizzled image, 64-wide rows: element (r,d) at r*64 + ((d>>3)^(r&7))*8 + (d&7)
__device__ __forceinline__ bf16x8 ldfrag_sw(const unsigned short* buf, int row, int chunk) {
  return *(const bf16x8*)(buf + (row << 6) + (((chunk) ^ (row & 7)) << 3));
}
// two stacked 64-row images (rows 0..127)
__device__ __forceinline__ bf16x8 ldfrag_k128(const unsigned short* buf, int row, int chunk) {
  return *(const bf16x8*)(buf + ((row >> 6) << 12) + ((row & 63) << 6) +
                          (((chunk) ^ (row & 7)) << 3));
}

// ====== convert: K -> 64-row tiles [hi 8KB | lo 8KB]; V -> V^T 64-s tiles [64d][64s];
//        zero(out); zero(zw+cnt); zero(po+pz) ======
__global__ __launch_bounds__(256) void convert_kernel(
    const float* __restrict__ kin, const float* __restrict__ vin,
    unsigned short* __restrict__ kimg, unsigned short* __restrict__ vt_g,
    float* __restrict__ out, float4* __restrict__ zw0, float4* __restrict__ po0) {
  __shared__ float vld[64][65];
  const int jb = blockIdx.x;
  const int tid = threadIdx.x;
  if (jb < 1024) {  // K: 32 bh x 32 tiles of 64 rows, hi/lo split
    const int bh = jb >> 5, tl = jb & 31;
    const float* src = kin + ((size_t)bh * 2048 + tl * 64) * 64;
    unsigned short* dst = kimg + (size_t)(bh * 32 + tl) * 8192;
#pragma unroll
    for (int g = 0; g < 2; ++g) {
      const int flat = g * 256 + tid;  // 512 chunks = 64 rows x 8
      const int r = flat >> 3, c = flat & 7;
      const float4 f0 = *(const float4*)(src + r * 64 + c * 8);
      const float4 f1 = *(const float4*)(src + r * 64 + c * 8 + 4);
      const float xs[8] = {f0.x, f0.y, f0.z, f0.w, f1.x, f1.y, f1.z, f1.w};
      bf16x8 hv, lv;
#pragma unroll
      for (int j = 0; j < 8; ++j) {
        const unsigned short h = bf16_rne(xs[j]);
        hv[j] = (short)h;
        lv[j] = (short)bf16_rne(xs[j] - bf16_to_f(h));
      }
      const int base = (r << 6) + ((c ^ (r & 7)) << 3);
      *(bf16x8*)(dst + base) = hv;
      *(bf16x8*)(dst + 4096 + base) = lv;
    }
  } else if (jb < 2048) {  // V^T: 32 bh x 32 tiles [64 d][64 s] swizzled
    const int jv = jb - 1024;
    const int bh = jv >> 5, tl = jv & 31;
    const float* src = vin + ((size_t)bh * 2048 + tl * 64) * 64;
#pragma unroll
    for (int g = 0; g < 4; ++g) {
      const int f = g * 256 + tid;  // 1024 float4s = 64 rows x 16
      const int r = f >> 4, c4 = f & 15;
      const float4 x = *(const float4*)(src + r * 64 + c4 * 4);
      vld[r][c4 * 4 + 0] = x.x;
      vld[r][c4 * 4 + 1] = x.y;
      vld[r][c4 * 4 + 2] = x.z;
      vld[r][c4 * 4 + 3] = x.w;
    }
    __syncthreads();
    unsigned short* dst = vt_g + (size_t)(bh * 32 + tl) * 4096;
#pragma unroll
    for (int g = 0; g < 2; ++g) {
      const int oc = g * 256 + tid;  // 512 chunks: d = oc>>3, sc = oc&7
      const int d = oc >> 3, sc = oc & 7;
      bf16x8 hv;
#pragma unroll
      for (int j = 0; j < 8; ++j) hv[j] = (short)bf16_rne(vld[sc * 8 + j][d]);
      *(bf16x8*)(dst + (d << 6) + ((sc ^ (d & 7)) << 3)) = hv;
    }
  } else if (jb < 2560) {  // zero d_out: 512 blocks x 2048 float4
    float4* o4 = (float4*)out;
    const size_t b = (size_t)(jb - 2048);
#pragma unroll
    for (int g = 0; g < 8; ++g)
      o4[b * 2048 + g * 256 + tid] = make_float4(0.f, 0.f, 0.f, 0.f);
  } else if (jb < 2593) {  // zero zw+cnt: 65,544 float4s
#pragma unroll
    for (int g = 0; g < 8; ++g) {
      const unsigned i = (unsigned)(jb - 2560) * 2048u + g * 256u + tid;
      if (i < 65544u) zw0[i] = make_float4(0.f, 0.f, 0.f, 0.f);
    }
  } else {  // zero po+pz: 332,800 float4s (163 blocks)
#pragma unroll
    for (int g = 0; g < 8; ++g) {
      const unsigned i = (unsigned)(jb - 2593) * 2048u + g * 256u + tid;
      if (i < 332800u) po0[i] = make_float4(0.f, 0.f, 0.f, 0.f);
    }
  }
}

// ====== Phase A: partial (Z,W) accumulated via global atomics; bf16x3 MFMA, BK=64 dbuf ======
// grid 2048: bh = b&31 (XCD-local), ttile = (b>>5)&15, squarter = b>>9 (8 tiles each)
__global__ __launch_bounds__(256, 4) void kl_score_mfma(
    const float* __restrict__ q, const unsigned short* __restrict__ kimg,
    float2* __restrict__ zw) {
  __shared__ __align__(16) unsigned short lbuf[2][8192];  // 2 x 16 KB
  const int b = blockIdx.x;
  const int bh = b & 31;
  const int t0 = ((b >> 5) & 15) * 128;
  const int sq = b >> 9;
  const int tid = threadIdx.x;
  const int lane = tid & 63, w = tid >> 6, quad = lane >> 4, l15 = lane & 15;
  const float* qb = q + (size_t)bh * (2048 * 64) + (size_t)t0 * 64;
  const unsigned short* kb = kimg + (size_t)bh * (32 * 8192);
  const int tg0 = sq * 8;

  // q tile -> hi image in lbuf[0], lo image in lbuf[1] (scaled by 0.125*log2e)
  // unroll 1: keep live float4s small (VGPR budget for 4 blocks/CU)
#pragma unroll 1
  for (int g = 0; g < 4; ++g) {
    const int flat = g * 256 + tid;  // 1024 chunks = 128 rows x 8
    const int r = flat >> 3, c = flat & 7;
    const float4 f0 = *(const float4*)(qb + r * 64 + c * 8);
    const float4 f1 = *(const float4*)(qb + r * 64 + c * 8 + 4);
    const float xs[8] = {f0.x, f0.y, f0.z, f0.w, f1.x, f1.y, f1.z, f1.w};
    bf16x8 hv, lv;
#pragma unroll
    for (int j = 0; j < 8; ++j) {
      const float x = xs[j] * SCL_Q;
      const unsigned short h = bf16_rne(x);
      hv[j] = (short)h;
      lv[j] = (short)bf16_rne(x - bf16_to_f(h));
    }
    const int r2 = r & 63, hi2 = r >> 6;
    const int base = hi2 * 4096 + (r2 << 6) + ((c ^ (r2 & 7)) << 3);
    *(bf16x8*)(&lbuf[0][0] + base) = hv;
    *(bf16x8*)(&lbuf[1][0] + base) = lv;
  }
  __syncthreads();

  bf16x8 ah[2][2], al[2][2];  // persistent q A-fragments (wave w: t-rows w*32..w*32+31)
#pragma unroll
  for (int rt = 0; rt < 2; ++rt) {
    const int row = w * 32 + rt * 16 + l15;
#pragma unroll
    for (int kc = 0; kc < 2; ++kc) {
      ah[rt][kc] = ldfrag_k128(&lbuf[0][0], row, kc * 4 + quad);
      al[rt][kc] = ldfrag_k128(&lbuf[1][0], row, kc * 4 + quad);
    }
  }
  __syncthreads();

  stage_img16(kb + (size_t)tg0 * 8192, &lbuf[0][0], lane, w);
  __syncthreads();  // drain tile 0

  float Zf[8], Wf[8];
#pragma unroll
  for (int i = 0; i < 8; ++i) { Zf[i] = 0.f; Wf[i] = 0.f; }

  // unroll 1: full unroll replicates prefetch/acc live ranges, blows the 128-VGPR
  // cap, spills ~2 KB/thread (R6: 2.16 GB HBM traffic, 640 us). Keep rolled.
#pragma unroll 1
  for (int t = 0; t < 8; ++t) {
    if (t < 7)
      stage_img16(kb + (size_t)(tg0 + t + 1) * 8192, &lbuf[(t + 1) & 1][0], lane, w);
    const unsigned short* cb = &lbuf[t & 1][0];  // [hi 4096 | lo 4096] elems, 64 rows

    f32x4 acc[2][4];
#pragma unroll
    for (int rt = 0; rt < 2; ++rt)
#pragma unroll
      for (int ct = 0; ct < 4; ++ct) acc[rt][ct] = (f32x4){0.f, 0.f, 0.f, 0.f};

#pragma unroll
    for (int ct = 0; ct < 4; ++ct) {
      const int srow = ct * 16 + l15;
      const bf16x8 bh0 = ldfrag_sw(cb, srow, quad);
      const bf16x8 bl0 = ldfrag_sw(cb + 4096, srow, quad);
      const bf16x8 bh1 = ldfrag_sw(cb, srow, 4 + quad);
      const bf16x8 bl1 = ldfrag_sw(cb + 4096, srow, 4 + quad);
#pragma unroll
      for (int rt = 0; rt < 2; ++rt) {
        f32x4 c = acc[rt][ct];
        c = __builtin_amdgcn_mfma_f32_16x16x32_bf16(ah[rt][0], bh0, c, 0, 0, 0);
        c = __builtin_amdgcn_mfma_f32_16x16x32_bf16(al[rt][0], bh0, c, 0, 0, 0);
        c = __builtin_amdgcn_mfma_f32_16x16x32_bf16(ah[rt][0], bl0, c, 0, 0, 0);
        c = __builtin_amdgcn_mfma_f32_16x16x32_bf16(ah[rt][1], bh1, c, 0, 0, 0);
        c = __builtin_amdgcn_mfma_f32_16x16x32_bf16(al[rt][1], bh1, c, 0, 0, 0);
        c = __builtin_amdgcn_mfma_f32_16x16x32_bf16(ah[rt][1], bl1, c, 0, 0, 0);
        acc[rt][ct] = c;
      }
    }

    // no-max epilogue (log2 domain): e = 2^t, W2 += e*t
#pragma unroll
    for (int rt = 0; rt < 2; ++rt)
#pragma unroll
      for (int r = 0; r < 4; ++r) {
        float zp = 0.f, wp = 0.f;
#pragma unroll
        for (int ct = 0; ct < 4; ++ct) {
          const float tt = acc[rt][ct][r];
          const float e = exp2f(tt);
          zp += e;
          wp = fmaf(e, tt, wp);
        }
        Zf[rt * 4 + r] += zp;
        Wf[rt * 4 + r] += wp;
      }
    __syncthreads();  // readers done; drains prefetch of t+1
  }

#pragma unroll
  for (int i = 0; i < 8; ++i) {
    float Zt = Zf[i], Wt = Wf[i];
#pragma unroll
    for (int mask = 1; mask <= 8; mask <<= 1) {
      Zt += __shfl_xor(Zt, mask);
      Wt += __shfl_xor(Wt, mask);
    }
    if (l15 == 0) {
      const int row = t0 + w * 32 + (i >> 2) * 16 + quad * 4 + (i & 3);
      float2* p = &zw[(size_t)bh * 2048 + row];
      atomicAdd(&p->x, Zt);
      atomicAdd(&p->y, Wt);
    }
  }
}

// ====== Phase B: rank-select exact top-614 set (order-invariant scatter) ======
__global__ __launch_bounds__(1024) void topk_kernel(const float2* __restrict__ zw,
                                                    int* __restrict__ topk,
                                                    int* __restrict__ cnt) {
  __shared__ __align__(16) float sv[2048];
  const int bh = blockIdx.x >> 1;
  const int half = blockIdx.x & 1;
  const int tid = threadIdx.x;
  for (int i = tid; i < 2048; i += 1024) {
    const float2 f = zw[(size_t)bh * 2048 + i];
    const double Z = (double)f.x, W = (double)f.y;
    sv[i] = (float)(LN2_D * (W / Z) - log(Z) + LOG_S_D);
  }
  __syncthreads();
  const int e = half * 1024 + tid;
  const float v = sv[e];
  int r = 0;
#pragma unroll 1
  for (int j = 0; j < 2048; j += 4) {
    const float4 x = *(const float4*)&sv[j];
    r += (x.x > v) || (x.x == v && (j + 0) < e);
    r += (x.y > v) || (x.y == v && (j + 1) < e);
    r += (x.z > v) || (x.z == v && (j + 2) < e);
    r += (x.w > v) || (x.w == v && (j + 3) < e);
  }
  if (r < U_SEL) topk[bh * U_SEL + atomicAdd(&cnt[bh], 1)] = e;
}

// ====== Phase C: high-occupancy bf16 MFMA attention, d-sliced PV, atomic O accum ======
// 64 q-rows/block, 64-s tiles; each wave computes a 16-s stripe of S^T, then owns a
// 16-wide d-slice of O reading ALL waves' P from shared LDS. No obuf, no LDS-atomic merge.
// grid 1280: bh = b&31 (XCD-local), rest = b>>5: lt = rest%10 (q-tile), sq = rest/10 (S quarter)
__global__ __launch_bounds__(256, 4) void sparse_attn_mfma(
    const float* __restrict__ q, const unsigned short* __restrict__ kimg,
    const unsigned short* __restrict__ vt_g, const int* __restrict__ topk,
    float* __restrict__ po, float* __restrict__ pz) {
  __shared__ __align__(16) unsigned short kt[4096];   // 8 KB, K tile [64 s][64 d] hi
  __shared__ __align__(16) unsigned short vt[4096];   // 8 KB, V^T tile [64 d][64 s]
  __shared__ __align__(16) unsigned short ps[64 * 68];  // 8.7 KB, P [qr][s], pitch 68
  __shared__ float zred[4][64];                         // 1 KB
  const int b = blockIdx.x;
  const int bh = b & 31;
  const int rest = b >> 5;
  const int lt = rest % LT_N;
  const int sq = rest / LT_N;
  const int l0 = lt * 64;
  const int t0 = sq * 8;  // 8 tiles of 64 s
  const int tid = threadIdx.x;
  const int lane = tid & 63, w = tid >> 6, quad = lane >> 4, l15 = lane & 15;
  const float* qb = q + (size_t)bh * (2048 * 64);
  const unsigned short* kb = kimg + (size_t)bh * (32 * 8192);
  const unsigned short* vtb = vt_g + (size_t)bh * (32 * 4096);
  const int* tkb = topk + bh * U_SEL;

  // gather selected q rows straight into B-fragments (x 0.125*log2e)
  bf16x8 qf[4][2];
#pragma unroll
  for (int nt = 0; nt < 4; ++nt) {
    const int l = l0 + nt * 16 + l15;
    const int row = tkb[l < U_SEL ? l : (U_SEL - 1)];
#pragma unroll
    for (int kc = 0; kc < 2; ++kc) {
      const float* qp = qb + (size_t)row * 64 + kc * 32 + quad * 8;
      const float4 f0 = *(const float4*)qp;
      const float4 f1 = *(const float4*)(qp + 4);
      const float xs[8] = {f0.x, f0.y, f0.z, f0.w, f1.x, f1.y, f1.z, f1.w};
      bf16x8 hv;
#pragma unroll
      for (int j = 0; j < 8; ++j) hv[j] = (short)bf16_rne(xs[j] * SCL_Q);
      qf[nt][kc] = hv;
    }
  }
  stage_img8(kb + (size_t)t0 * 8192, kt, lane, w);       // hi half of 64-row tile
  stage_img8(vtb + (size_t)t0 * 4096, vt, lane, w);
  __syncthreads();

  float zrun[4] = {0.f, 0.f, 0.f, 0.f};
  f32x4 oacc[4];
#pragma unroll
  for (int a = 0; a < 4; ++a) oacc[a] = (f32x4){0.f, 0.f, 0.f, 0.f};

  // unroll 1: spill guard (see kl_score comment)
#pragma unroll 1
  for (int t = 0; t < 8; ++t) {
    // S^T = K·q^T : wave w computes s-stripe [w*16, +16) x all 64 qr
    const int arow = w * 16 + l15;
    const bf16x8 a0 = ldfrag_sw(kt, arow, quad);
    const bf16x8 a1 = ldfrag_sw(kt, arow, 4 + quad);
    f32x4 sacc[4];
#pragma unroll
    for (int nt = 0; nt < 4; ++nt) {
      f32x4 c = (f32x4){0.f, 0.f, 0.f, 0.f};
      c = __builtin_amdgcn_mfma_f32_16x16x32_bf16(a0, qf[nt][0], c, 0, 0, 0);
      c = __builtin_amdgcn_mfma_f32_16x16x32_bf16(a1, qf[nt][1], c, 0, 0, 0);
      sacc[nt] = c;
    }
    // no-max softmax: p = 2^t; write P stripe to shared ps
#pragma unroll
    for (int nt = 0; nt < 4; ++nt) {
      float zl = 0.f;
      bf16x4 pw;
#pragma unroll
      for (int r = 0; r < 4; ++r) {
        const float p = exp2f(sacc[nt][r]);
        zl += p;
        pw[r] = (short)bf16_rne(p);
      }
      *(bf16x4*)&ps[(nt * 16 + l15) * 68 + w * 16 + quad * 4] = pw;
      zrun[nt] += zl;
    }
    __syncthreads();  // P visible to all waves

    // PV: wave w owns d-slice [w*16, +16): O[qr][d] += P[qr][s]·V^T[d][s] over 64 s
#pragma unroll
    for (int c = 0; c < 2; ++c) {
      const bf16x8 vb = ldfrag_sw(vt, w * 16 + l15, c * 4 + quad);
#pragma unroll
      for (int mtq = 0; mtq < 4; ++mtq) {
        const bf16x8 pa = *(const bf16x8*)&ps[(mtq * 16 + l15) * 68 + c * 32 + quad * 8];
        oacc[mtq] = __builtin_amdgcn_mfma_f32_16x16x32_bf16(pa, vb, oacc[mtq], 0, 0, 0);
      }
    }
    __syncthreads();  // kt/vt/ps reads done
    if (t < 7) {
      stage_img8(kb + (size_t)(t0 + t + 1) * 8192, kt, lane, w);
      stage_img8(vtb + (size_t)(t0 + t + 1) * 4096, vt, lane, w);
      __syncthreads();  // drain staging
    }
  }

  // Z: reduce over quads (shfl) + waves (LDS), atomic-accumulate across sq splits
#pragma unroll
  for (int nt = 0; nt < 4; ++nt) {
    float z = zrun[nt];
    z += __shfl_xor(z, 16);
    z += __shfl_xor(z, 32);
    if (quad == 0) zred[w][nt * 16 + l15] = z;
  }
  __syncthreads();
  if (tid < 64)
    atomicAdd(&pz[(bh * LT_N + lt) * 64 + tid],
              zred[0][tid] + zred[1][tid] + zred[2][tid] + zred[3][tid]);
  // O: each wave stores its d-slice via global atomics (sums the 4 sq splits)
  float* pob = po + (size_t)(bh * LT_N + lt) * 4096 + w * 16 + l15;
#pragma unroll
  for (int mtq = 0; mtq < 4; ++mtq)
#pragma unroll
    for (int r = 0; r < 4; ++r) {
      const int qr = mtq * 16 + quad * 4 + r;
      atomicAdd(pob + qr * 64, oacc[mtq][r]);
    }
}

// ====== merge: out[tkb[l]] = po/pz ======
// grid 320: bh = b&31, lt = b>>5
__global__ __launch_bounds__(256) void merge_kernel(
    const float* __restrict__ po, const float* __restrict__ pz,
    const int* __restrict__ topk, float* __restrict__ out) {
  __shared__ float zs[64];
  const int b = blockIdx.x;
  const int bh = b & 31;
  const int lt = b >> 5;
  const int tid = threadIdx.x;
  const int* tkb = topk + bh * U_SEL;
  if (tid < 64) zs[tid] = pz[(bh * LT_N + lt) * 64 + tid];
  __syncthreads();
  const float4* p0 = (const float4*)(po + (size_t)(bh * LT_N + lt) * 4096);
#pragma unroll
  for (int g = 0; g < 4; ++g) {
    const int i = g * 256 + tid;  // float4 index: qr = i>>4
    const int qr = i >> 4;
    const int l = lt * 64 + qr;
    if (l < U_SEL) {
      const int row = tkb[l];
      const float inv = 1.0f / zs[qr];
      const float4 a = p0[i];
      float4 o;
      o.x = a.x * inv;
      o.y = a.y * inv;
      o.z = a.z * inv;
      o.w = a.w * inv;
      ((float4*)out)[((size_t)bh * 2048 + row) * 16 + (i & 15)] = o;
    }
  }
}

extern "C" void kernel_launch(void* const* d_in, const int* in_sizes, int n_in,
                              void* d_out, int out_size, void* d_ws, size_t ws_size,
                              hipStream_t stream) {
  const float* q = (const float*)d_in[0];
  const float* k = (const float*)d_in[1];
  const float* v = (const float*)d_in[2];
  float* out = (float*)d_out;
  char* ws = (char*)d_ws;
  float2* zw = (float2*)(ws + WS_ZW);
  int* cnt = (int*)(ws + WS_CNT);
  int* topk = (int*)(ws + WS_TOPK);
  float* po = (float*)(ws + WS_PO);
  float* pz = (float*)(ws + WS_PZ);
  unsigned short* kimg = (unsigned short*)(ws + WS_KIMG);
  unsigned short* vt_g = (unsigned short*)(ws + WS_VT);

  convert_kernel<<<dim3(2756), dim3(256), 0, stream>>>(k, v, kimg, vt_g, out,
                                                       (float4*)(ws + WS_ZW),
                                                       (float4*)(ws + WS_PO));
  kl_score_mfma<<<dim3(2048), dim3(256), 0, stream>>>(q, kimg, zw);
  topk_kernel<<<dim3(64), dim3(1024), 0, stream>>>(zw, topk, cnt);
  sparse_attn_mfma<<<dim3(1280), dim3(256), 0, stream>>>(q, kimg, vt_g, topk, po, pz);
  merge_kernel<<<dim3(320), dim3(256), 0, stream>>>(po, pz, topk, out);
}